// Round 1
// baseline (4997.923 us; speedup 1.0000x reference)
//
#include <hip/hip_runtime.h>

#define N_NODES 50000
#define N_EDGES 800000
#define N_GRAPHS 500
#define BN_EPS 1e-5f
#define F 256          // hidden feature width (all layers output 256)

// ---------------- degree / dinv ----------------
__global__ void k_deg(const int* __restrict__ dst, float* __restrict__ deg) {
    int e = blockIdx.x * blockDim.x + threadIdx.x;
    if (e < N_EDGES) atomicAdd(&deg[dst[e]], 1.0f);
}

__global__ void k_dinv(float* __restrict__ deg) {
    int n = blockIdx.x * blockDim.x + threadIdx.x;
    if (n < N_NODES) deg[n] = rsqrtf(deg[n] + 1.0f);   // deg of A+I
}

// ---------------- fp32 tiled GEMM: C[M,N] = A[M,K] * B[K,N] ----------------
// BM=BN=128, BK=8, 256 threads, 8x8 per thread.
__global__ __launch_bounds__(256)
void k_gemm(const float* __restrict__ A, const float* __restrict__ B,
            float* __restrict__ C, int M, int N, int K) {
    __shared__ float As[8][128];
    __shared__ float Bs[8][128];
    const int tid = threadIdx.x;
    const int brow = blockIdx.x * 128;
    const int bcol = blockIdx.y * 128;
    const int tx = tid & 15, ty = tid >> 4;

    float acc[8][8];
    #pragma unroll
    for (int i = 0; i < 8; ++i)
        #pragma unroll
        for (int j = 0; j < 8; ++j) acc[i][j] = 0.f;

    for (int k0 = 0; k0 < K; k0 += 8) {
        // A tile: 128 rows x 8 cols = 1024 floats -> each thread one float4
        {
            int r = tid >> 1;            // 2 float4 per row
            int c = (tid & 1) * 4;
            float4 v = make_float4(0.f, 0.f, 0.f, 0.f);
            int gr = brow + r;
            if (gr < M) v = *reinterpret_cast<const float4*>(&A[(size_t)gr * K + k0 + c]);
            As[c + 0][r] = v.x; As[c + 1][r] = v.y; As[c + 2][r] = v.z; As[c + 3][r] = v.w;
        }
        // B tile: 8 rows x 128 cols
        {
            int r = tid >> 5;            // 32 float4 per row
            int c = (tid & 31) * 4;
            float4 v = *reinterpret_cast<const float4*>(&B[(size_t)(k0 + r) * N + bcol + c]);
            *reinterpret_cast<float4*>(&Bs[r][c]) = v;
        }
        __syncthreads();
        #pragma unroll
        for (int k = 0; k < 8; ++k) {
            float a[8], b[8];
            #pragma unroll
            for (int j = 0; j < 8; ++j) a[j] = As[k][ty * 8 + j];
            #pragma unroll
            for (int j = 0; j < 8; ++j) b[j] = Bs[k][tx * 8 + j];
            #pragma unroll
            for (int i = 0; i < 8; ++i)
                #pragma unroll
                for (int j = 0; j < 8; ++j)
                    acc[i][j] = fmaf(a[i], b[j], acc[i][j]);
        }
        __syncthreads();
    }

    #pragma unroll
    for (int i = 0; i < 8; ++i) {
        int gr = brow + ty * 8 + i;
        if (gr >= M) continue;
        #pragma unroll
        for (int j = 0; j < 8; j += 4) {
            float4 v = make_float4(acc[i][j], acc[i][j + 1], acc[i][j + 2], acc[i][j + 3]);
            *reinterpret_cast<float4*>(&C[(size_t)gr * N + bcol + tx * 8 + j]) = v;
        }
    }
}

// ---------------- self-loop init: agg[n,f] = dinv[n]^2 * xw[n,f] ----------------
__global__ void k_selfinit(const float* __restrict__ xw, const float* __restrict__ dinv,
                           float* __restrict__ agg) {
    int idx = blockIdx.x * blockDim.x + threadIdx.x;       // over N_NODES*F/4
    if (idx >= N_NODES * (F / 4)) return;
    int n = idx / (F / 4);
    float d = dinv[n];
    float s = d * d;
    float4 v = reinterpret_cast<const float4*>(xw)[idx];
    v.x *= s; v.y *= s; v.z *= s; v.w *= s;
    reinterpret_cast<float4*>(agg)[idx] = v;
}

// ---------------- edge aggregation (atomics) ----------------
template<int EPB>
__global__ __launch_bounds__(F)
void k_edges(const int* __restrict__ src, const int* __restrict__ dst,
             const float* __restrict__ dinv, const float* __restrict__ xw,
             float* __restrict__ agg) {
    const int f = threadIdx.x;                 // 256 threads = feature dim
    const int e0 = blockIdx.x * EPB;
    #pragma unroll
    for (int i = 0; i < EPB; ++i) {
        int e = e0 + i;
        int s = src[e], d = dst[e];
        float norm = dinv[s] * dinv[d];
        atomicAdd(&agg[(size_t)d * F + f], norm * xw[(size_t)s * F + f]);
    }
}

// ---------------- bias + ReLU + BN-stats accumulation ----------------
template<int ROWS>
__global__ __launch_bounds__(F)
void k_post_bnstats(float* __restrict__ h, const float* __restrict__ bias,
                    float* __restrict__ stats) {
    const int f = threadIdx.x;
    const int r0 = blockIdx.x * ROWS;
    const float b = bias[f];
    float s = 0.f, s2 = 0.f;
    for (int i = 0; i < ROWS; ++i) {
        int n = r0 + i;
        if (n >= N_NODES) break;
        float v = h[(size_t)n * F + f] + b;
        v = fmaxf(v, 0.f);
        h[(size_t)n * F + f] = v;
        s += v; s2 += v * v;
    }
    atomicAdd(&stats[f], s);
    atomicAdd(&stats[F + f], s2);
}

// ---------------- BN apply (in place) ----------------
__global__ void k_bnapply(float* __restrict__ h, const float* __restrict__ stats,
                          const float* __restrict__ gamma, const float* __restrict__ beta) {
    int idx = blockIdx.x * blockDim.x + threadIdx.x;
    if (idx >= N_NODES * F) return;
    int f = idx & (F - 1);
    float mean = stats[f] * (1.0f / N_NODES);
    float var  = stats[F + f] * (1.0f / N_NODES) - mean * mean;
    float a = gamma[f] * rsqrtf(var + BN_EPS);
    h[idx] = (h[idx] - mean) * a + beta[f];
}

// ---------------- final layer: bias + ReLU + global_add_pool ----------------
template<int ROWS>
__global__ __launch_bounds__(F)
void k_post_pool(const float* __restrict__ h, const float* __restrict__ bias,
                 const int* __restrict__ batch, float* __restrict__ out) {
    const int f = threadIdx.x;
    const int r0 = blockIdx.x * ROWS;
    const float b = bias[f];
    float acc = 0.f;
    int cur = -1;
    for (int i = 0; i < ROWS; ++i) {
        int n = r0 + i;
        if (n >= N_NODES) break;
        int g = batch[n];
        float v = fmaxf(h[(size_t)n * F + f] + b, 0.f);
        if (g != cur) {
            if (cur >= 0) atomicAdd(&out[(size_t)cur * F + f], acc);
            cur = g; acc = v;
        } else {
            acc += v;
        }
    }
    if (cur >= 0) atomicAdd(&out[(size_t)cur * F + f], acc);
}

// ---------------- host ----------------
extern "C" void kernel_launch(void* const* d_in, const int* in_sizes, int n_in,
                              void* d_out, int out_size, void* d_ws, size_t ws_size,
                              hipStream_t stream) {
    const float* x     = (const float*)d_in[0];
    const int*   ei    = (const int*)d_in[1];
    const int*   batch = (const int*)d_in[2];
    const float* W[6], *bias[6], *gamma[5], *beta[5];
    for (int i = 0; i < 6; ++i) {
        W[i]    = (const float*)d_in[3 + 2 * i];
        bias[i] = (const float*)d_in[4 + 2 * i];
    }
    for (int i = 0; i < 5; ++i) {
        gamma[i] = (const float*)d_in[15 + 2 * i];
        beta[i]  = (const float*)d_in[16 + 2 * i];
    }
    float* out = (float*)d_out;

    char* ws = (char*)d_ws;
    const size_t HBYTES = (size_t)N_NODES * F * sizeof(float);   // 51.2 MB
    float* deg   = (float*)ws;                                    // 50000 f (becomes dinv)
    float* bufA  = (float*)(ws + 200704);                         // xw
    float* bufB  = (float*)(ws + 200704 + HBYTES);                // agg / h
    float* stats = (float*)(ws + 200704 + 2 * HBYTES);            // 2*F floats

    const int* src = ei;
    const int* dst = ei + N_EDGES;

    hipMemsetAsync(deg, 0, N_NODES * sizeof(float), stream);
    hipMemsetAsync(out, 0, (size_t)N_GRAPHS * F * sizeof(float), stream);
    k_deg<<<(N_EDGES + 255) / 256, 256, 0, stream>>>(dst, deg);
    k_dinv<<<(N_NODES + 255) / 256, 256, 0, stream>>>(deg);

    const float* hin = x;
    for (int l = 0; l < 6; ++l) {
        const int K = (l == 0) ? 128 : 256;
        dim3 grid((N_NODES + 127) / 128, F / 128);
        k_gemm<<<grid, 256, 0, stream>>>(hin, W[l], bufA, N_NODES, F, K);

        int tot4 = N_NODES * (F / 4);
        k_selfinit<<<(tot4 + 255) / 256, 256, 0, stream>>>(bufA, deg, bufB);
        k_edges<16><<<N_EDGES / 16, F, 0, stream>>>(src, dst, deg, bufA, bufB);

        if (l < 5) {
            hipMemsetAsync(stats, 0, 2 * F * sizeof(float), stream);
            k_post_bnstats<128><<<(N_NODES + 127) / 128, F, 0, stream>>>(bufB, bias[l], stats);
            k_bnapply<<<(N_NODES * F + 255) / 256, 256, 0, stream>>>(bufB, stats, gamma[l], beta[l]);
            hin = bufB;
        } else {
            k_post_pool<128><<<(N_NODES + 127) / 128, F, 0, stream>>>(bufB, bias[l], batch, out);
        }
    }
}

// Round 2
// 1887.062 us; speedup vs baseline: 2.6485x; 2.6485x over previous
//
#include <hip/hip_runtime.h>

#define N_NODES 50000
#define N_EDGES 800000
#define N_GRAPHS 500
#define BN_EPS 1e-5f
#define F 256
#define SCAN_BLOCKS ((N_NODES + 255) / 256)   // 196

// ---------------- degree histogram (int) ----------------
__global__ void k_hist(const int* __restrict__ dst, int* __restrict__ cnt) {
    int e = blockIdx.x * blockDim.x + threadIdx.x;
    if (e < N_EDGES) atomicAdd(&cnt[dst[e]], 1);
}

__global__ void k_dinv(const int* __restrict__ cnt, float* __restrict__ dinv) {
    int n = blockIdx.x * blockDim.x + threadIdx.x;
    if (n < N_NODES) dinv[n] = rsqrtf((float)cnt[n] + 1.0f);   // deg of A+I
}

// ---------------- prefix scan (3 tiny kernels) ----------------
__global__ void k_scan1(const int* __restrict__ cnt, int* __restrict__ rowptr,
                        int* __restrict__ bsum) {
    __shared__ int s[256];
    int tid = threadIdx.x;
    int i = blockIdx.x * 256 + tid;
    int v = (i < N_NODES) ? cnt[i] : 0;
    s[tid] = v;
    __syncthreads();
    for (int off = 1; off < 256; off <<= 1) {
        int add = (tid >= off) ? s[tid - off] : 0;
        __syncthreads();
        s[tid] += add;
        __syncthreads();
    }
    if (i < N_NODES) rowptr[i] = s[tid] - v;        // exclusive within block
    if (tid == 255) bsum[blockIdx.x] = s[255];
}

__global__ void k_scan2(int* __restrict__ bsum) {    // exclusive scan in place
    __shared__ int s[256];
    int tid = threadIdx.x;
    int v = (tid < SCAN_BLOCKS) ? bsum[tid] : 0;
    s[tid] = v;
    __syncthreads();
    for (int off = 1; off < 256; off <<= 1) {
        int add = (tid >= off) ? s[tid - off] : 0;
        __syncthreads();
        s[tid] += add;
        __syncthreads();
    }
    if (tid < SCAN_BLOCKS) bsum[tid] = s[tid] - v;
}

__global__ void k_scan3(int* __restrict__ rowptr, const int* __restrict__ bsum) {
    int i = blockIdx.x * 256 + threadIdx.x;
    if (i < N_NODES) rowptr[i] += bsum[blockIdx.x];
    if (i == 0) rowptr[N_NODES] = N_EDGES;
}

// ---------------- scatter edges into CSR ----------------
__global__ void k_scatter(const int* __restrict__ src, const int* __restrict__ dst,
                          const float* __restrict__ dinv, const int* __restrict__ rowptr,
                          int* __restrict__ fill, int* __restrict__ esrc,
                          float* __restrict__ enorm) {
    int e = blockIdx.x * 256 + threadIdx.x;
    if (e >= N_EDGES) return;
    int s = src[e], d = dst[e];
    int slot = rowptr[d] + atomicAdd(&fill[d], 1);
    esrc[slot] = s;
    enorm[slot] = dinv[s] * dinv[d];
}

// ---------------- fp32 tiled GEMM with fused BN-apply on A ----------------
// C[M,N] = BN(A)[M,K] * B[K,N];  BN(A)[r,k] = A[r,k]*mulk[k] + addk[k]
__global__ __launch_bounds__(256)
void k_gemm(const float* __restrict__ A, const float* __restrict__ B,
            float* __restrict__ C, int M, int N, int K,
            const float* __restrict__ mulk, const float* __restrict__ addk) {
    __shared__ float As[8][128];
    __shared__ float Bs[8][128];
    const int tid = threadIdx.x;
    const int brow = blockIdx.x * 128;
    const int bcol = blockIdx.y * 128;
    const int tx = tid & 15, ty = tid >> 4;

    float acc[8][8];
    #pragma unroll
    for (int i = 0; i < 8; ++i)
        #pragma unroll
        for (int j = 0; j < 8; ++j) acc[i][j] = 0.f;

    for (int k0 = 0; k0 < K; k0 += 8) {
        {
            int r = tid >> 1;
            int c = (tid & 1) * 4;
            float4 v = make_float4(0.f, 0.f, 0.f, 0.f);
            int gr = brow + r;
            if (gr < M) v = *reinterpret_cast<const float4*>(&A[(size_t)gr * K + k0 + c]);
            if (mulk) {
                float4 mk = *reinterpret_cast<const float4*>(&mulk[k0 + c]);
                float4 ak = *reinterpret_cast<const float4*>(&addk[k0 + c]);
                v.x = fmaf(v.x, mk.x, ak.x);
                v.y = fmaf(v.y, mk.y, ak.y);
                v.z = fmaf(v.z, mk.z, ak.z);
                v.w = fmaf(v.w, mk.w, ak.w);
            }
            As[c + 0][r] = v.x; As[c + 1][r] = v.y; As[c + 2][r] = v.z; As[c + 3][r] = v.w;
        }
        {
            int r = tid >> 5;
            int c = (tid & 31) * 4;
            float4 v = *reinterpret_cast<const float4*>(&B[(size_t)(k0 + r) * N + bcol + c]);
            *reinterpret_cast<float4*>(&Bs[r][c]) = v;
        }
        __syncthreads();
        #pragma unroll
        for (int k = 0; k < 8; ++k) {
            float a[8], b[8];
            #pragma unroll
            for (int j = 0; j < 8; ++j) a[j] = As[k][ty * 8 + j];
            #pragma unroll
            for (int j = 0; j < 8; ++j) b[j] = Bs[k][tx * 8 + j];
            #pragma unroll
            for (int i = 0; i < 8; ++i)
                #pragma unroll
                for (int j = 0; j < 8; ++j)
                    acc[i][j] = fmaf(a[i], b[j], acc[i][j]);
        }
        __syncthreads();
    }

    #pragma unroll
    for (int i = 0; i < 8; ++i) {
        int gr = brow + ty * 8 + i;
        if (gr >= M) continue;
        #pragma unroll
        for (int j = 0; j < 8; j += 4) {
            float4 v = make_float4(acc[i][j], acc[i][j + 1], acc[i][j + 2], acc[i][j + 3]);
            *reinterpret_cast<float4*>(&C[(size_t)gr * N + bcol + tx * 8 + j]) = v;
        }
    }
}

// ---------------- CSR aggregation: one wave per dst node, fused bias+ReLU ----
__global__ __launch_bounds__(256)
void k_agg(const float* __restrict__ xw, const float* __restrict__ dinv,
           const int* __restrict__ rowptr, const int* __restrict__ esrc,
           const float* __restrict__ enorm, const float* __restrict__ bias,
           float* __restrict__ h) {
    const int lane = threadIdx.x & 63;
    const int wave = threadIdx.x >> 6;
    const int n = blockIdx.x * 4 + wave;
    if (n >= N_NODES) return;
    const float4* xw4 = reinterpret_cast<const float4*>(xw);

    float d = dinv[n];
    float sl = d * d;
    float4 acc = xw4[(size_t)n * 64 + lane];
    acc.x *= sl; acc.y *= sl; acc.z *= sl; acc.w *= sl;

    const int beg = rowptr[n], end = rowptr[n + 1];
    #pragma unroll 2
    for (int i = beg; i < end; ++i) {
        int s = esrc[i];
        float w = enorm[i];
        float4 v = xw4[(size_t)s * 64 + lane];
        acc.x = fmaf(w, v.x, acc.x);
        acc.y = fmaf(w, v.y, acc.y);
        acc.z = fmaf(w, v.z, acc.z);
        acc.w = fmaf(w, v.w, acc.w);
    }
    float4 b4 = reinterpret_cast<const float4*>(bias)[lane];
    acc.x = fmaxf(acc.x + b4.x, 0.f);
    acc.y = fmaxf(acc.y + b4.y, 0.f);
    acc.z = fmaxf(acc.z + b4.z, 0.f);
    acc.w = fmaxf(acc.w + b4.w, 0.f);
    reinterpret_cast<float4*>(h)[(size_t)n * 64 + lane] = acc;
}

// ---------------- BN stats (read-only) ----------------
template<int ROWS>
__global__ __launch_bounds__(256)
void k_bnstats(const float* __restrict__ h, float* __restrict__ stats) {
    const int f = threadIdx.x;
    const int r0 = blockIdx.x * ROWS;
    float s = 0.f, s2 = 0.f;
    for (int i = 0; i < ROWS; ++i) {
        int n = r0 + i;
        if (n >= N_NODES) break;
        float v = h[(size_t)n * F + f];
        s += v; s2 += v * v;
    }
    atomicAdd(&stats[f], s);
    atomicAdd(&stats[F + f], s2);
}

__global__ void k_bnfinalize(const float* __restrict__ stats,
                             const float* __restrict__ gamma, const float* __restrict__ beta,
                             float* __restrict__ mulk, float* __restrict__ addk) {
    int f = threadIdx.x;
    float m = stats[f] * (1.0f / N_NODES);
    float var = stats[F + f] * (1.0f / N_NODES) - m * m;
    float sc = gamma[f] * rsqrtf(var + BN_EPS);
    mulk[f] = sc;
    addk[f] = beta[f] - m * sc;
}

// ---------------- global_add_pool (batch sorted, run-length + atomics) -------
template<int ROWS>
__global__ __launch_bounds__(256)
void k_pool(const float* __restrict__ h, const int* __restrict__ batch,
            float* __restrict__ out) {
    const int f = threadIdx.x;
    const int r0 = blockIdx.x * ROWS;
    float acc = 0.f;
    int cur = -1;
    for (int i = 0; i < ROWS; ++i) {
        int n = r0 + i;
        if (n >= N_NODES) break;
        int g = batch[n];
        float v = h[(size_t)n * F + f];
        if (g != cur) {
            if (cur >= 0) atomicAdd(&out[(size_t)cur * F + f], acc);
            cur = g; acc = v;
        } else {
            acc += v;
        }
    }
    if (cur >= 0) atomicAdd(&out[(size_t)cur * F + f], acc);
}

// ---------------- host ----------------
extern "C" void kernel_launch(void* const* d_in, const int* in_sizes, int n_in,
                              void* d_out, int out_size, void* d_ws, size_t ws_size,
                              hipStream_t stream) {
    const float* x     = (const float*)d_in[0];
    const int*   ei    = (const int*)d_in[1];
    const int*   batch = (const int*)d_in[2];
    const float* W[6], *bias[6], *gamma[5], *beta[5];
    for (int i = 0; i < 6; ++i) {
        W[i]    = (const float*)d_in[3 + 2 * i];
        bias[i] = (const float*)d_in[4 + 2 * i];
    }
    for (int i = 0; i < 5; ++i) {
        gamma[i] = (const float*)d_in[15 + 2 * i];
        beta[i]  = (const float*)d_in[16 + 2 * i];
    }
    float* out = (float*)d_out;

    char* ws = (char*)d_ws;
    size_t off = 0;
    auto alloc = [&](size_t bytes) {
        void* p = ws + off;
        off = (off + bytes + 255) & ~(size_t)255;
        return p;
    };
    int*   cnt    = (int*)  alloc(N_NODES * 4);        // histogram, reused as fill
    int*   rowptr = (int*)  alloc((N_NODES + 1) * 4);
    int*   bsum   = (int*)  alloc(256 * 4);
    float* dinv   = (float*)alloc(N_NODES * 4);
    int*   esrc   = (int*)  alloc((size_t)N_EDGES * 4);
    float* enorm  = (float*)alloc((size_t)N_EDGES * 4);
    float* mulk   = (float*)alloc(F * 4);
    float* addk   = (float*)alloc(F * 4);
    float* stats  = (float*)alloc(2 * F * 4);
    float* bufA   = (float*)alloc((size_t)N_NODES * F * 4);   // xw
    float* bufB   = (float*)alloc((size_t)N_NODES * F * 4);   // h

    const int* src = ei;
    const int* dst = ei + N_EDGES;

    // ---- CSR build + dinv (per call; ws is re-poisoned) ----
    hipMemsetAsync(cnt, 0, N_NODES * 4, stream);
    hipMemsetAsync(out, 0, (size_t)N_GRAPHS * F * 4, stream);
    k_hist<<<(N_EDGES + 255) / 256, 256, 0, stream>>>(dst, cnt);
    k_dinv<<<(N_NODES + 255) / 256, 256, 0, stream>>>(cnt, dinv);
    k_scan1<<<SCAN_BLOCKS, 256, 0, stream>>>(cnt, rowptr, bsum);
    k_scan2<<<1, 256, 0, stream>>>(bsum);
    k_scan3<<<SCAN_BLOCKS, 256, 0, stream>>>(rowptr, bsum);
    hipMemsetAsync(cnt, 0, N_NODES * 4, stream);       // reuse as fill
    k_scatter<<<(N_EDGES + 255) / 256, 256, 0, stream>>>(src, dst, dinv, rowptr, cnt, esrc, enorm);

    const float* hin = x;
    for (int l = 0; l < 6; ++l) {
        const int K = (l == 0) ? 128 : 256;
        const float* mk = (l == 0) ? nullptr : mulk;
        const float* ak = (l == 0) ? nullptr : addk;
        dim3 grid((N_NODES + 127) / 128, F / 128);
        k_gemm<<<grid, 256, 0, stream>>>(hin, W[l], bufA, N_NODES, F, K, mk, ak);

        k_agg<<<(N_NODES + 3) / 4, 256, 0, stream>>>(bufA, dinv, rowptr, esrc, enorm, bias[l], bufB);

        if (l < 5) {
            hipMemsetAsync(stats, 0, 2 * F * 4, stream);
            k_bnstats<256><<<(N_NODES + 255) / 256, 256, 0, stream>>>(bufB, stats);
            k_bnfinalize<<<1, F, 0, stream>>>(stats, gamma[l], beta[l], mulk, addk);
            hin = bufB;
        } else {
            k_pool<128><<<(N_NODES + 127) / 128, 256, 0, stream>>>(bufB, batch, out);
        }
    }
}

// Round 3
// 1782.779 us; speedup vs baseline: 2.8034x; 1.0585x over previous
//
#include <hip/hip_runtime.h>

#define N_NODES 50000
#define N_EDGES 800000
#define N_GRAPHS 500
#define BN_EPS 1e-5f
#define F 256
#define SCAN_BLOCKS ((N_NODES + 255) / 256)   // 196

typedef short short8 __attribute__((ext_vector_type(8)));
typedef float f32x4 __attribute__((ext_vector_type(4)));

// ---------------- degree histogram (int) ----------------
__global__ void k_hist(const int* __restrict__ dst, int* __restrict__ cnt) {
    int e = blockIdx.x * blockDim.x + threadIdx.x;
    if (e < N_EDGES) atomicAdd(&cnt[dst[e]], 1);
}

__global__ void k_dinv(const int* __restrict__ cnt, float* __restrict__ dinv) {
    int n = blockIdx.x * blockDim.x + threadIdx.x;
    if (n < N_NODES) dinv[n] = rsqrtf((float)cnt[n] + 1.0f);
}

// ---------------- prefix scan ----------------
__global__ void k_scan1(const int* __restrict__ cnt, int* __restrict__ rowptr,
                        int* __restrict__ bsum) {
    __shared__ int s[256];
    int tid = threadIdx.x;
    int i = blockIdx.x * 256 + tid;
    int v = (i < N_NODES) ? cnt[i] : 0;
    s[tid] = v;
    __syncthreads();
    for (int off = 1; off < 256; off <<= 1) {
        int add = (tid >= off) ? s[tid - off] : 0;
        __syncthreads();
        s[tid] += add;
        __syncthreads();
    }
    if (i < N_NODES) rowptr[i] = s[tid] - v;
    if (tid == 255) bsum[blockIdx.x] = s[255];
}

__global__ void k_scan2(int* __restrict__ bsum) {
    __shared__ int s[256];
    int tid = threadIdx.x;
    int v = (tid < SCAN_BLOCKS) ? bsum[tid] : 0;
    s[tid] = v;
    __syncthreads();
    for (int off = 1; off < 256; off <<= 1) {
        int add = (tid >= off) ? s[tid - off] : 0;
        __syncthreads();
        s[tid] += add;
        __syncthreads();
    }
    if (tid < SCAN_BLOCKS) bsum[tid] = s[tid] - v;
}

__global__ void k_scan3(int* __restrict__ rowptr, const int* __restrict__ bsum) {
    int i = blockIdx.x * 256 + threadIdx.x;
    if (i < N_NODES) rowptr[i] += bsum[blockIdx.x];
    if (i == 0) rowptr[N_NODES] = N_EDGES;
}

// ---------------- scatter edges into CSR ----------------
__global__ void k_scatter(const int* __restrict__ src, const int* __restrict__ dst,
                          const float* __restrict__ dinv, const int* __restrict__ rowptr,
                          int* __restrict__ fill, int* __restrict__ esrc,
                          float* __restrict__ enorm) {
    int e = blockIdx.x * 256 + threadIdx.x;
    if (e >= N_EDGES) return;
    int s = src[e], d = dst[e];
    int slot = rowptr[d] + atomicAdd(&fill[d], 1);
    esrc[slot] = s;
    enorm[slot] = dinv[s] * dinv[d];
}

// ---------------- weight prepack: W[K][256] f32 -> Wt_hi/Wt_lo [256][K] bf16 --
__global__ void k_pack(const float* __restrict__ W, short* __restrict__ hi,
                       short* __restrict__ lo, int K) {
    int idx = blockIdx.x * 256 + threadIdx.x;   // over 256*K
    if (idx >= 256 * K) return;
    int n = idx / K, k = idx - n * K;
    float f = W[(size_t)k * 256 + n];
    unsigned u = __builtin_bit_cast(unsigned, f);
    hi[idx] = (short)(u >> 16);                 // truncation split
    float hf = __builtin_bit_cast(float, u & 0xFFFF0000u);
    lo[idx] = (short)(__builtin_bit_cast(unsigned, f - hf) >> 16);
}

// ---------------- split-bf16 MFMA GEMM with fused BN-apply on A --------------
// C[M,256] = BN(A)[M,K] * B[K,256];  B given prepacked/transposed hi/lo [256][K]
#define BK 32
__global__ __launch_bounds__(256)
void k_gemm_mfma(const float* __restrict__ A, const short* __restrict__ Bhi,
                 const short* __restrict__ Blo, float* __restrict__ C,
                 int M, int K,
                 const float* __restrict__ mulk, const float* __restrict__ addk) {
    // LDS: [hi/lo][128 rows][16 uints = 32 bf16], XOR-swizzled 16B units
    __shared__ unsigned As[2][128 * 16];
    const int tid  = threadIdx.x;
    const int lane = tid & 63;
    const int w    = tid >> 6;
    const int wr   = (w >> 1) * 64;
    const int wc   = (w & 1) * 64;
    const int brow = blockIdx.x * 128;
    const int bcol = blockIdx.y * 128;

    f32x4 acc[4][4];
    #pragma unroll
    for (int m = 0; m < 4; ++m)
        #pragma unroll
        for (int n = 0; n < 4; ++n) acc[m][n] = (f32x4){0.f, 0.f, 0.f, 0.f};

    // A prefetch: thread -> row lr = tid>>1, k-window lk = (tid&1)*16, 16 floats
    const int lr = tid >> 1;
    const int lk = (tid & 1) * 16;
    const int grow = brow + lr;
    const bool rowok = grow < M;
    const float* Aptr = A + (size_t)grow * K + lk;
    const int NS = K / BK;

    float4 pf0, pf1, pf2, pf3;
    auto load_pf = [&](int s) {
        if (rowok) {
            const float* p = Aptr + s * BK;
            pf0 = *reinterpret_cast<const float4*>(p);
            pf1 = *reinterpret_cast<const float4*>(p + 4);
            pf2 = *reinterpret_cast<const float4*>(p + 8);
            pf3 = *reinterpret_cast<const float4*>(p + 12);
        } else {
            pf0 = pf1 = pf2 = pf3 = make_float4(0.f, 0.f, 0.f, 0.f);
        }
    };

    load_pf(0);

    for (int s = 0; s < NS; ++s) {
        __syncthreads();     // previous compute done reading LDS
        {   // stage: BN-apply, split hi/lo, swizzled LDS write
            float vals[16];
            vals[0]=pf0.x; vals[1]=pf0.y; vals[2]=pf0.z; vals[3]=pf0.w;
            vals[4]=pf1.x; vals[5]=pf1.y; vals[6]=pf1.z; vals[7]=pf1.w;
            vals[8]=pf2.x; vals[9]=pf2.y; vals[10]=pf2.z; vals[11]=pf2.w;
            vals[12]=pf3.x; vals[13]=pf3.y; vals[14]=pf3.z; vals[15]=pf3.w;
            if (mulk) {
                int kabs = s * BK + lk;
                #pragma unroll
                for (int q = 0; q < 4; ++q) {
                    float4 mk = *reinterpret_cast<const float4*>(&mulk[kabs + 4 * q]);
                    float4 ak = *reinterpret_cast<const float4*>(&addk[kabs + 4 * q]);
                    vals[4*q+0] = fmaf(vals[4*q+0], mk.x, ak.x);
                    vals[4*q+1] = fmaf(vals[4*q+1], mk.y, ak.y);
                    vals[4*q+2] = fmaf(vals[4*q+2], mk.z, ak.z);
                    vals[4*q+3] = fmaf(vals[4*q+3], mk.w, ak.w);
                }
            }
            unsigned hiw[8], low[8];
            #pragma unroll
            for (int p = 0; p < 8; ++p) {
                float f0 = vals[2*p], f1 = vals[2*p+1];
                unsigned u0 = __builtin_bit_cast(unsigned, f0);
                unsigned u1 = __builtin_bit_cast(unsigned, f1);
                hiw[p] = (u1 & 0xFFFF0000u) | (u0 >> 16);
                float h0 = __builtin_bit_cast(float, u0 & 0xFFFF0000u);
                float h1 = __builtin_bit_cast(float, u1 & 0xFFFF0000u);
                unsigned l0 = __builtin_bit_cast(unsigned, f0 - h0);
                unsigned l1 = __builtin_bit_cast(unsigned, f1 - h1);
                low[p] = (l1 & 0xFFFF0000u) | (l0 >> 16);
            }
            const int sw = (lr >> 1) & 3;
            const int c0 = (tid & 1) * 2;          // 16B unit index 0..3
            unsigned* dh0 = &As[0][lr * 16 + ((c0 ^ sw) << 2)];
            unsigned* dh1 = &As[0][lr * 16 + (((c0 + 1) ^ sw) << 2)];
            unsigned* dl0 = &As[1][lr * 16 + ((c0 ^ sw) << 2)];
            unsigned* dl1 = &As[1][lr * 16 + (((c0 + 1) ^ sw) << 2)];
            *reinterpret_cast<uint4*>(dh0) = make_uint4(hiw[0], hiw[1], hiw[2], hiw[3]);
            *reinterpret_cast<uint4*>(dh1) = make_uint4(hiw[4], hiw[5], hiw[6], hiw[7]);
            *reinterpret_cast<uint4*>(dl0) = make_uint4(low[0], low[1], low[2], low[3]);
            *reinterpret_cast<uint4*>(dl1) = make_uint4(low[4], low[5], low[6], low[7]);
        }
        if (s + 1 < NS) load_pf(s + 1);   // overlap next A load with compute
        __syncthreads();

        // B fragments: direct global (L2-resident), layout [n][K]
        short8 bh[4], bl[4];
        const int kb = s * BK + (lane >> 4) * 8;
        #pragma unroll
        for (int n = 0; n < 4; ++n) {
            int col = bcol + wc + n * 16 + (lane & 15);
            bh[n] = *reinterpret_cast<const short8*>(Bhi + (size_t)col * K + kb);
            bl[n] = *reinterpret_cast<const short8*>(Blo + (size_t)col * K + kb);
        }
        #pragma unroll
        for (int m = 0; m < 4; ++m) {
            int row = wr + m * 16 + (lane & 15);
            int c = lane >> 4;
            int sw = (row >> 1) & 3;
            const unsigned* ph = &As[0][row * 16 + ((c ^ sw) << 2)];
            const unsigned* pl = &As[1][row * 16 + ((c ^ sw) << 2)];
            short8 ah = *reinterpret_cast<const short8*>(ph);
            short8 al = *reinterpret_cast<const short8*>(pl);
            #pragma unroll
            for (int n = 0; n < 4; ++n) {
                acc[m][n] = __builtin_amdgcn_mfma_f32_16x16x32_bf16(ah, bh[n], acc[m][n], 0, 0, 0);
                acc[m][n] = __builtin_amdgcn_mfma_f32_16x16x32_bf16(al, bh[n], acc[m][n], 0, 0, 0);
                acc[m][n] = __builtin_amdgcn_mfma_f32_16x16x32_bf16(ah, bl[n], acc[m][n], 0, 0, 0);
            }
        }
    }

    // epilogue: C/D layout col=lane&15, row=(lane>>4)*4+reg
    #pragma unroll
    for (int m = 0; m < 4; ++m) {
        #pragma unroll
        for (int n = 0; n < 4; ++n) {
            int col = bcol + wc + n * 16 + (lane & 15);
            #pragma unroll
            for (int j = 0; j < 4; ++j) {
                int row = brow + wr + m * 16 + (lane >> 4) * 4 + j;
                if (row < M) C[(size_t)row * 256 + col] = acc[m][n][j];
            }
        }
    }
}

// ---------------- CSR aggregation: one wave per dst node, fused bias+ReLU ----
__global__ __launch_bounds__(256)
void k_agg(const float* __restrict__ xw, const float* __restrict__ dinv,
           const int* __restrict__ rowptr, const int* __restrict__ esrc,
           const float* __restrict__ enorm, const float* __restrict__ bias,
           float* __restrict__ h) {
    const int lane = threadIdx.x & 63;
    const int wave = threadIdx.x >> 6;
    const int n = blockIdx.x * 4 + wave;
    if (n >= N_NODES) return;
    const float4* xw4 = reinterpret_cast<const float4*>(xw);

    float d = dinv[n];
    float sl = d * d;
    float4 acc = xw4[(size_t)n * 64 + lane];
    acc.x *= sl; acc.y *= sl; acc.z *= sl; acc.w *= sl;

    const int beg = rowptr[n], end = rowptr[n + 1];
    int i = beg;
    for (; i + 4 <= end; i += 4) {
        int s0 = esrc[i], s1 = esrc[i + 1], s2 = esrc[i + 2], s3 = esrc[i + 3];
        float w0 = enorm[i], w1 = enorm[i + 1], w2 = enorm[i + 2], w3 = enorm[i + 3];
        float4 v0 = xw4[(size_t)s0 * 64 + lane];
        float4 v1 = xw4[(size_t)s1 * 64 + lane];
        float4 v2 = xw4[(size_t)s2 * 64 + lane];
        float4 v3 = xw4[(size_t)s3 * 64 + lane];
        acc.x = fmaf(w0, v0.x, acc.x); acc.y = fmaf(w0, v0.y, acc.y);
        acc.z = fmaf(w0, v0.z, acc.z); acc.w = fmaf(w0, v0.w, acc.w);
        acc.x = fmaf(w1, v1.x, acc.x); acc.y = fmaf(w1, v1.y, acc.y);
        acc.z = fmaf(w1, v1.z, acc.z); acc.w = fmaf(w1, v1.w, acc.w);
        acc.x = fmaf(w2, v2.x, acc.x); acc.y = fmaf(w2, v2.y, acc.y);
        acc.z = fmaf(w2, v2.z, acc.z); acc.w = fmaf(w2, v2.w, acc.w);
        acc.x = fmaf(w3, v3.x, acc.x); acc.y = fmaf(w3, v3.y, acc.y);
        acc.z = fmaf(w3, v3.z, acc.z); acc.w = fmaf(w3, v3.w, acc.w);
    }
    for (; i < end; ++i) {
        int s = esrc[i];
        float wgt = enorm[i];
        float4 v = xw4[(size_t)s * 64 + lane];
        acc.x = fmaf(wgt, v.x, acc.x); acc.y = fmaf(wgt, v.y, acc.y);
        acc.z = fmaf(wgt, v.z, acc.z); acc.w = fmaf(wgt, v.w, acc.w);
    }
    float4 b4 = reinterpret_cast<const float4*>(bias)[lane];
    acc.x = fmaxf(acc.x + b4.x, 0.f);
    acc.y = fmaxf(acc.y + b4.y, 0.f);
    acc.z = fmaxf(acc.z + b4.z, 0.f);
    acc.w = fmaxf(acc.w + b4.w, 0.f);
    reinterpret_cast<float4*>(h)[(size_t)n * 64 + lane] = acc;
}

// ---------------- BN stats (read-only) ----------------
template<int ROWS>
__global__ __launch_bounds__(256)
void k_bnstats(const float* __restrict__ h, float* __restrict__ stats) {
    const int f = threadIdx.x;
    const int r0 = blockIdx.x * ROWS;
    float s = 0.f, s2 = 0.f;
    for (int i = 0; i < ROWS; ++i) {
        int n = r0 + i;
        if (n >= N_NODES) break;
        float v = h[(size_t)n * F + f];
        s += v; s2 += v * v;
    }
    atomicAdd(&stats[f], s);
    atomicAdd(&stats[F + f], s2);
}

__global__ void k_bnfinalize(const float* __restrict__ stats,
                             const float* __restrict__ gamma, const float* __restrict__ beta,
                             float* __restrict__ mulk, float* __restrict__ addk) {
    int f = threadIdx.x;
    float m = stats[f] * (1.0f / N_NODES);
    float var = stats[F + f] * (1.0f / N_NODES) - m * m;
    float sc = gamma[f] * rsqrtf(var + BN_EPS);
    mulk[f] = sc;
    addk[f] = beta[f] - m * sc;
}

// ---------------- global_add_pool ----------------
template<int ROWS>
__global__ __launch_bounds__(256)
void k_pool(const float* __restrict__ h, const int* __restrict__ batch,
            float* __restrict__ out) {
    const int f = threadIdx.x;
    const int r0 = blockIdx.x * ROWS;
    float acc = 0.f;
    int cur = -1;
    for (int i = 0; i < ROWS; ++i) {
        int n = r0 + i;
        if (n >= N_NODES) break;
        int g = batch[n];
        float v = h[(size_t)n * F + f];
        if (g != cur) {
            if (cur >= 0) atomicAdd(&out[(size_t)cur * F + f], acc);
            cur = g; acc = v;
        } else {
            acc += v;
        }
    }
    if (cur >= 0) atomicAdd(&out[(size_t)cur * F + f], acc);
}

// ---------------- host ----------------
extern "C" void kernel_launch(void* const* d_in, const int* in_sizes, int n_in,
                              void* d_out, int out_size, void* d_ws, size_t ws_size,
                              hipStream_t stream) {
    const float* x     = (const float*)d_in[0];
    const int*   ei    = (const int*)d_in[1];
    const int*   batch = (const int*)d_in[2];
    const float* W[6], *bias[6], *gamma[5], *beta[5];
    for (int i = 0; i < 6; ++i) {
        W[i]    = (const float*)d_in[3 + 2 * i];
        bias[i] = (const float*)d_in[4 + 2 * i];
    }
    for (int i = 0; i < 5; ++i) {
        gamma[i] = (const float*)d_in[15 + 2 * i];
        beta[i]  = (const float*)d_in[16 + 2 * i];
    }
    float* out = (float*)d_out;

    char* ws = (char*)d_ws;
    size_t off = 0;
    auto alloc = [&](size_t bytes) {
        void* p = ws + off;
        off = (off + bytes + 255) & ~(size_t)255;
        return p;
    };
    int*   cnt    = (int*)  alloc(N_NODES * 4);
    int*   rowptr = (int*)  alloc((N_NODES + 1) * 4);
    int*   bsum   = (int*)  alloc(256 * 4);
    float* dinv   = (float*)alloc(N_NODES * 4);
    int*   esrc   = (int*)  alloc((size_t)N_EDGES * 4);
    float* enorm  = (float*)alloc((size_t)N_EDGES * 4);
    float* mulk   = (float*)alloc(F * 4);
    float* addk   = (float*)alloc(F * 4);
    float* stats  = (float*)alloc(2 * F * 4);
    short* Whi[6]; short* Wlo[6];
    for (int l = 0; l < 6; ++l) {
        int K = (l == 0) ? 128 : 256;
        Whi[l] = (short*)alloc((size_t)256 * K * 2);
        Wlo[l] = (short*)alloc((size_t)256 * K * 2);
    }
    float* bufA = (float*)alloc((size_t)N_NODES * F * 4);   // xw
    float* bufB = (float*)alloc((size_t)N_NODES * F * 4);   // h

    const int* src = ei;
    const int* dst = ei + N_EDGES;

    // ---- CSR build + dinv + weight prepack ----
    hipMemsetAsync(cnt, 0, N_NODES * 4, stream);
    hipMemsetAsync(out, 0, (size_t)N_GRAPHS * F * 4, stream);
    k_hist<<<(N_EDGES + 255) / 256, 256, 0, stream>>>(dst, cnt);
    k_dinv<<<(N_NODES + 255) / 256, 256, 0, stream>>>(cnt, dinv);
    k_scan1<<<SCAN_BLOCKS, 256, 0, stream>>>(cnt, rowptr, bsum);
    k_scan2<<<1, 256, 0, stream>>>(bsum);
    k_scan3<<<SCAN_BLOCKS, 256, 0, stream>>>(rowptr, bsum);
    hipMemsetAsync(cnt, 0, N_NODES * 4, stream);
    k_scatter<<<(N_EDGES + 255) / 256, 256, 0, stream>>>(src, dst, dinv, rowptr, cnt, esrc, enorm);
    for (int l = 0; l < 6; ++l) {
        int K = (l == 0) ? 128 : 256;
        k_pack<<<(256 * K + 255) / 256, 256, 0, stream>>>(W[l], Whi[l], Wlo[l], K);
    }

    const float* hin = x;
    for (int l = 0; l < 6; ++l) {
        const int K = (l == 0) ? 128 : 256;
        const float* mk = (l == 0) ? nullptr : mulk;
        const float* ak = (l == 0) ? nullptr : addk;
        dim3 grid((N_NODES + 127) / 128, 2);
        k_gemm_mfma<<<grid, 256, 0, stream>>>(hin, Whi[l], Wlo[l], bufA, N_NODES, K, mk, ak);

        k_agg<<<(N_NODES + 3) / 4, 256, 0, stream>>>(bufA, dinv, rowptr, esrc, enorm, bias[l], bufB);

        if (l < 5) {
            hipMemsetAsync(stats, 0, 2 * F * 4, stream);
            k_bnstats<256><<<(N_NODES + 255) / 256, 256, 0, stream>>>(bufB, stats);
            k_bnfinalize<<<1, F, 0, stream>>>(stats, gamma[l], beta[l], mulk, addk);
            hin = bufB;
        } else {
            k_pool<128><<<(N_NODES + 127) / 128, 256, 0, stream>>>(bufB, batch, out);
        }
    }
}

// Round 4
// 1338.545 us; speedup vs baseline: 3.7338x; 1.3319x over previous
//
#include <hip/hip_runtime.h>

#define N_NODES 50000
#define N_EDGES 800000
#define N_GRAPHS 500
#define BN_EPS 1e-5f
#define F 256
#define SCAN_BLOCKS ((N_NODES + 255) / 256)   // 196

typedef short short8 __attribute__((ext_vector_type(8)));
typedef float f32x4 __attribute__((ext_vector_type(4)));
typedef _Float16 h16x4 __attribute__((ext_vector_type(4)));

// ---------------- degree histogram (int) ----------------
__global__ void k_hist(const int* __restrict__ dst, int* __restrict__ cnt) {
    int e = blockIdx.x * blockDim.x + threadIdx.x;
    if (e < N_EDGES) atomicAdd(&cnt[dst[e]], 1);
}

__global__ void k_dinv(const int* __restrict__ cnt, float* __restrict__ dinv) {
    int n = blockIdx.x * blockDim.x + threadIdx.x;
    if (n < N_NODES) dinv[n] = rsqrtf((float)cnt[n] + 1.0f);
}

// ---------------- prefix scan ----------------
__global__ void k_scan1(const int* __restrict__ cnt, int* __restrict__ rowptr,
                        int* __restrict__ bsum) {
    __shared__ int s[256];
    int tid = threadIdx.x;
    int i = blockIdx.x * 256 + tid;
    int v = (i < N_NODES) ? cnt[i] : 0;
    s[tid] = v;
    __syncthreads();
    for (int off = 1; off < 256; off <<= 1) {
        int add = (tid >= off) ? s[tid - off] : 0;
        __syncthreads();
        s[tid] += add;
        __syncthreads();
    }
    if (i < N_NODES) rowptr[i] = s[tid] - v;
    if (tid == 255) bsum[blockIdx.x] = s[255];
}

__global__ void k_scan2(int* __restrict__ bsum) {
    __shared__ int s[256];
    int tid = threadIdx.x;
    int v = (tid < SCAN_BLOCKS) ? bsum[tid] : 0;
    s[tid] = v;
    __syncthreads();
    for (int off = 1; off < 256; off <<= 1) {
        int add = (tid >= off) ? s[tid - off] : 0;
        __syncthreads();
        s[tid] += add;
        __syncthreads();
    }
    if (tid < SCAN_BLOCKS) bsum[tid] = s[tid] - v;
}

__global__ void k_scan3(int* __restrict__ rowptr, const int* __restrict__ bsum) {
    int i = blockIdx.x * 256 + threadIdx.x;
    if (i < N_NODES) rowptr[i] += bsum[blockIdx.x];
    if (i == 0) rowptr[N_NODES] = N_EDGES;
}

// ---------------- scatter edges into CSR ----------------
__global__ void k_scatter(const int* __restrict__ src, const int* __restrict__ dst,
                          const float* __restrict__ dinv, const int* __restrict__ rowptr,
                          int* __restrict__ fill, int* __restrict__ esrc,
                          float* __restrict__ enorm) {
    int e = blockIdx.x * 256 + threadIdx.x;
    if (e >= N_EDGES) return;
    int s = src[e], d = dst[e];
    int slot = rowptr[d] + atomicAdd(&fill[d], 1);
    esrc[slot] = s;
    enorm[slot] = dinv[s] * dinv[d];
}

// ---------------- weight prepack: W[K][256] f32 -> Wt_hi/Wt_lo [256][K] bf16 --
__global__ void k_pack(const float* __restrict__ W, short* __restrict__ hi,
                       short* __restrict__ lo, int K) {
    int idx = blockIdx.x * 256 + threadIdx.x;
    if (idx >= 256 * K) return;
    int n = idx / K, k = idx - n * K;
    float f = W[(size_t)k * 256 + n];
    unsigned u = __builtin_bit_cast(unsigned, f);
    hi[idx] = (short)(u >> 16);
    float hf = __builtin_bit_cast(float, u & 0xFFFF0000u);
    lo[idx] = (short)(__builtin_bit_cast(unsigned, f - hf) >> 16);
}

// ---------------- split-bf16 MFMA GEMM, fused BN-apply on A, fp16 C ----------
#define BK 32
__global__ __launch_bounds__(256)
void k_gemm_mfma(const float* __restrict__ A, const short* __restrict__ Bhi,
                 const short* __restrict__ Blo, _Float16* __restrict__ C,
                 int M, int K,
                 const float* __restrict__ mulk, const float* __restrict__ addk) {
    __shared__ unsigned As[2][128 * 16];
    const int tid  = threadIdx.x;
    const int lane = tid & 63;
    const int w    = tid >> 6;
    const int wr   = (w >> 1) * 64;
    const int wc   = (w & 1) * 64;
    const int brow = blockIdx.x * 128;
    const int bcol = blockIdx.y * 128;

    f32x4 acc[4][4];
    #pragma unroll
    for (int m = 0; m < 4; ++m)
        #pragma unroll
        for (int n = 0; n < 4; ++n) acc[m][n] = (f32x4){0.f, 0.f, 0.f, 0.f};

    const int lr = tid >> 1;
    const int lk = (tid & 1) * 16;
    const int grow = brow + lr;
    const bool rowok = grow < M;
    const float* Aptr = A + (size_t)grow * K + lk;
    const int NS = K / BK;

    float4 pf0, pf1, pf2, pf3;
    auto load_pf = [&](int s) {
        if (rowok) {
            const float* p = Aptr + s * BK;
            pf0 = *reinterpret_cast<const float4*>(p);
            pf1 = *reinterpret_cast<const float4*>(p + 4);
            pf2 = *reinterpret_cast<const float4*>(p + 8);
            pf3 = *reinterpret_cast<const float4*>(p + 12);
        } else {
            pf0 = pf1 = pf2 = pf3 = make_float4(0.f, 0.f, 0.f, 0.f);
        }
    };

    load_pf(0);

    for (int s = 0; s < NS; ++s) {
        __syncthreads();
        {
            float vals[16];
            vals[0]=pf0.x; vals[1]=pf0.y; vals[2]=pf0.z; vals[3]=pf0.w;
            vals[4]=pf1.x; vals[5]=pf1.y; vals[6]=pf1.z; vals[7]=pf1.w;
            vals[8]=pf2.x; vals[9]=pf2.y; vals[10]=pf2.z; vals[11]=pf2.w;
            vals[12]=pf3.x; vals[13]=pf3.y; vals[14]=pf3.z; vals[15]=pf3.w;
            if (mulk) {
                int kabs = s * BK + lk;
                #pragma unroll
                for (int q = 0; q < 4; ++q) {
                    float4 mk = *reinterpret_cast<const float4*>(&mulk[kabs + 4 * q]);
                    float4 ak = *reinterpret_cast<const float4*>(&addk[kabs + 4 * q]);
                    vals[4*q+0] = fmaf(vals[4*q+0], mk.x, ak.x);
                    vals[4*q+1] = fmaf(vals[4*q+1], mk.y, ak.y);
                    vals[4*q+2] = fmaf(vals[4*q+2], mk.z, ak.z);
                    vals[4*q+3] = fmaf(vals[4*q+3], mk.w, ak.w);
                }
            }
            unsigned hiw[8], low[8];
            #pragma unroll
            for (int p = 0; p < 8; ++p) {
                float f0 = vals[2*p], f1 = vals[2*p+1];
                unsigned u0 = __builtin_bit_cast(unsigned, f0);
                unsigned u1 = __builtin_bit_cast(unsigned, f1);
                hiw[p] = (u1 & 0xFFFF0000u) | (u0 >> 16);
                float h0 = __builtin_bit_cast(float, u0 & 0xFFFF0000u);
                float h1 = __builtin_bit_cast(float, u1 & 0xFFFF0000u);
                unsigned l0 = __builtin_bit_cast(unsigned, f0 - h0);
                unsigned l1 = __builtin_bit_cast(unsigned, f1 - h1);
                low[p] = (l1 & 0xFFFF0000u) | (l0 >> 16);
            }
            const int sw = (lr >> 1) & 3;
            const int c0 = (tid & 1) * 2;
            unsigned* dh0 = &As[0][lr * 16 + ((c0 ^ sw) << 2)];
            unsigned* dh1 = &As[0][lr * 16 + (((c0 + 1) ^ sw) << 2)];
            unsigned* dl0 = &As[1][lr * 16 + ((c0 ^ sw) << 2)];
            unsigned* dl1 = &As[1][lr * 16 + (((c0 + 1) ^ sw) << 2)];
            *reinterpret_cast<uint4*>(dh0) = make_uint4(hiw[0], hiw[1], hiw[2], hiw[3]);
            *reinterpret_cast<uint4*>(dh1) = make_uint4(hiw[4], hiw[5], hiw[6], hiw[7]);
            *reinterpret_cast<uint4*>(dl0) = make_uint4(low[0], low[1], low[2], low[3]);
            *reinterpret_cast<uint4*>(dl1) = make_uint4(low[4], low[5], low[6], low[7]);
        }
        if (s + 1 < NS) load_pf(s + 1);
        __syncthreads();

        short8 bh[4], bl[4];
        const int kb = s * BK + (lane >> 4) * 8;
        #pragma unroll
        for (int n = 0; n < 4; ++n) {
            int col = bcol + wc + n * 16 + (lane & 15);
            bh[n] = *reinterpret_cast<const short8*>(Bhi + (size_t)col * K + kb);
            bl[n] = *reinterpret_cast<const short8*>(Blo + (size_t)col * K + kb);
        }
        #pragma unroll
        for (int m = 0; m < 4; ++m) {
            int row = wr + m * 16 + (lane & 15);
            int c = lane >> 4;
            int sw = (row >> 1) & 3;
            const unsigned* ph = &As[0][row * 16 + ((c ^ sw) << 2)];
            const unsigned* pl = &As[1][row * 16 + ((c ^ sw) << 2)];
            short8 ah = *reinterpret_cast<const short8*>(ph);
            short8 al = *reinterpret_cast<const short8*>(pl);
            #pragma unroll
            for (int n = 0; n < 4; ++n) {
                acc[m][n] = __builtin_amdgcn_mfma_f32_16x16x32_bf16(ah, bh[n], acc[m][n], 0, 0, 0);
                acc[m][n] = __builtin_amdgcn_mfma_f32_16x16x32_bf16(al, bh[n], acc[m][n], 0, 0, 0);
                acc[m][n] = __builtin_amdgcn_mfma_f32_16x16x32_bf16(ah, bl[n], acc[m][n], 0, 0, 0);
            }
        }
    }

    #pragma unroll
    for (int m = 0; m < 4; ++m) {
        #pragma unroll
        for (int n = 0; n < 4; ++n) {
            int col = bcol + wc + n * 16 + (lane & 15);
            #pragma unroll
            for (int j = 0; j < 4; ++j) {
                int row = brow + wr + m * 16 + (lane >> 4) * 4 + j;
                if (row < M) C[(size_t)row * 256 + col] = (_Float16)acc[m][n][j];
            }
        }
    }
}

// ---------------- fused aggregation ------------------------------------------
// MODE 0: h = relu(agg + bias) written fp32; BN-stats accumulated to stats.
// MODE 1: final layer — pooled directly into out via run-length + atomics.
// 16 nodes / block: 4 waves x 4 serial nodes. Lane owns features 4*lane..+3.
template<int MODE>
__global__ __launch_bounds__(256)
void k_agg_fused(const _Float16* __restrict__ xw, const float* __restrict__ dinv,
                 const int* __restrict__ rowptr, const int* __restrict__ esrc,
                 const float* __restrict__ enorm, const float* __restrict__ bias,
                 float* __restrict__ h, float* __restrict__ stats,
                 const int* __restrict__ batch, float* __restrict__ out) {
    __shared__ float red[8][256];
    const int lane = threadIdx.x & 63;
    const int wave = threadIdx.x >> 6;
    const int fb = lane << 2;
    const h16x4* xw4 = reinterpret_cast<const h16x4*>(xw);
    float4 b4 = reinterpret_cast<const float4*>(bias)[lane];

    float4 ssum = make_float4(0.f, 0.f, 0.f, 0.f);
    float4 ssq  = make_float4(0.f, 0.f, 0.f, 0.f);
    int curg = -1;
    float4 pacc = make_float4(0.f, 0.f, 0.f, 0.f);

    #pragma unroll
    for (int t = 0; t < 4; ++t) {
        int n = blockIdx.x * 16 + wave * 4 + t;
        if (n >= N_NODES) break;
        float d = dinv[n];
        float sl = d * d;
        h16x4 sv = xw4[(size_t)n * 64 + lane];
        float4 acc = make_float4(sl * (float)sv.x, sl * (float)sv.y,
                                 sl * (float)sv.z, sl * (float)sv.w);
        const int beg = rowptr[n], end = rowptr[n + 1];
        int i = beg;
        for (; i + 4 <= end; i += 4) {
            int s0 = esrc[i], s1 = esrc[i+1], s2 = esrc[i+2], s3 = esrc[i+3];
            float w0 = enorm[i], w1 = enorm[i+1], w2 = enorm[i+2], w3 = enorm[i+3];
            h16x4 v0 = xw4[(size_t)s0 * 64 + lane];
            h16x4 v1 = xw4[(size_t)s1 * 64 + lane];
            h16x4 v2 = xw4[(size_t)s2 * 64 + lane];
            h16x4 v3 = xw4[(size_t)s3 * 64 + lane];
            acc.x = fmaf(w0, (float)v0.x, acc.x); acc.y = fmaf(w0, (float)v0.y, acc.y);
            acc.z = fmaf(w0, (float)v0.z, acc.z); acc.w = fmaf(w0, (float)v0.w, acc.w);
            acc.x = fmaf(w1, (float)v1.x, acc.x); acc.y = fmaf(w1, (float)v1.y, acc.y);
            acc.z = fmaf(w1, (float)v1.z, acc.z); acc.w = fmaf(w1, (float)v1.w, acc.w);
            acc.x = fmaf(w2, (float)v2.x, acc.x); acc.y = fmaf(w2, (float)v2.y, acc.y);
            acc.z = fmaf(w2, (float)v2.z, acc.z); acc.w = fmaf(w2, (float)v2.w, acc.w);
            acc.x = fmaf(w3, (float)v3.x, acc.x); acc.y = fmaf(w3, (float)v3.y, acc.y);
            acc.z = fmaf(w3, (float)v3.z, acc.z); acc.w = fmaf(w3, (float)v3.w, acc.w);
        }
        for (; i < end; ++i) {
            int s = esrc[i];
            float wg = enorm[i];
            h16x4 v = xw4[(size_t)s * 64 + lane];
            acc.x = fmaf(wg, (float)v.x, acc.x); acc.y = fmaf(wg, (float)v.y, acc.y);
            acc.z = fmaf(wg, (float)v.z, acc.z); acc.w = fmaf(wg, (float)v.w, acc.w);
        }
        acc.x = fmaxf(acc.x + b4.x, 0.f);
        acc.y = fmaxf(acc.y + b4.y, 0.f);
        acc.z = fmaxf(acc.z + b4.z, 0.f);
        acc.w = fmaxf(acc.w + b4.w, 0.f);

        if (MODE == 0) {
            reinterpret_cast<float4*>(h)[(size_t)n * 64 + lane] = acc;
            ssum.x += acc.x; ssum.y += acc.y; ssum.z += acc.z; ssum.w += acc.w;
            ssq.x = fmaf(acc.x, acc.x, ssq.x); ssq.y = fmaf(acc.y, acc.y, ssq.y);
            ssq.z = fmaf(acc.z, acc.z, ssq.z); ssq.w = fmaf(acc.w, acc.w, ssq.w);
        } else {
            int g = batch[n];
            if (g != curg) {
                if (curg >= 0) {
                    atomicAdd(&out[(size_t)curg * 256 + fb + 0], pacc.x);
                    atomicAdd(&out[(size_t)curg * 256 + fb + 1], pacc.y);
                    atomicAdd(&out[(size_t)curg * 256 + fb + 2], pacc.z);
                    atomicAdd(&out[(size_t)curg * 256 + fb + 3], pacc.w);
                }
                curg = g; pacc = acc;
            } else {
                pacc.x += acc.x; pacc.y += acc.y; pacc.z += acc.z; pacc.w += acc.w;
            }
        }
    }

    if (MODE == 0) {
        *reinterpret_cast<float4*>(&red[wave][fb])     = ssum;
        *reinterpret_cast<float4*>(&red[4 + wave][fb]) = ssq;
        __syncthreads();
        int t = threadIdx.x;
        float s = red[0][t] + red[1][t] + red[2][t] + red[3][t];
        float q = red[4][t] + red[5][t] + red[6][t] + red[7][t];
        atomicAdd(&stats[t], s);
        atomicAdd(&stats[256 + t], q);
    } else {
        if (curg >= 0) {
            atomicAdd(&out[(size_t)curg * 256 + fb + 0], pacc.x);
            atomicAdd(&out[(size_t)curg * 256 + fb + 1], pacc.y);
            atomicAdd(&out[(size_t)curg * 256 + fb + 2], pacc.z);
            atomicAdd(&out[(size_t)curg * 256 + fb + 3], pacc.w);
        }
    }
}

__global__ void k_bnfinalize(const float* __restrict__ stats,
                             const float* __restrict__ gamma, const float* __restrict__ beta,
                             float* __restrict__ mulk, float* __restrict__ addk) {
    int f = threadIdx.x;
    float m = stats[f] * (1.0f / N_NODES);
    float var = stats[F + f] * (1.0f / N_NODES) - m * m;
    float sc = gamma[f] * rsqrtf(var + BN_EPS);
    mulk[f] = sc;
    addk[f] = beta[f] - m * sc;
}

// ---------------- host ----------------
extern "C" void kernel_launch(void* const* d_in, const int* in_sizes, int n_in,
                              void* d_out, int out_size, void* d_ws, size_t ws_size,
                              hipStream_t stream) {
    const float* x     = (const float*)d_in[0];
    const int*   ei    = (const int*)d_in[1];
    const int*   batch = (const int*)d_in[2];
    const float* W[6], *bias[6], *gamma[5], *beta[5];
    for (int i = 0; i < 6; ++i) {
        W[i]    = (const float*)d_in[3 + 2 * i];
        bias[i] = (const float*)d_in[4 + 2 * i];
    }
    for (int i = 0; i < 5; ++i) {
        gamma[i] = (const float*)d_in[15 + 2 * i];
        beta[i]  = (const float*)d_in[16 + 2 * i];
    }
    float* out = (float*)d_out;

    char* ws = (char*)d_ws;
    size_t off = 0;
    auto alloc = [&](size_t bytes) {
        void* p = ws + off;
        off = (off + bytes + 255) & ~(size_t)255;
        return p;
    };
    int*   cnt      = (int*)  alloc(N_NODES * 4);
    int*   rowptr   = (int*)  alloc((N_NODES + 1) * 4);
    int*   bsum     = (int*)  alloc(256 * 4);
    float* dinv     = (float*)alloc(N_NODES * 4);
    int*   esrc     = (int*)  alloc((size_t)N_EDGES * 4);
    float* enorm    = (float*)alloc((size_t)N_EDGES * 4);
    float* mulk     = (float*)alloc(F * 4);
    float* addk     = (float*)alloc(F * 4);
    float* statsAll = (float*)alloc(5 * 2 * F * 4);
    short* Whi[6]; short* Wlo[6];
    for (int l = 0; l < 6; ++l) {
        int K = (l == 0) ? 128 : 256;
        Whi[l] = (short*)alloc((size_t)256 * K * 2);
        Wlo[l] = (short*)alloc((size_t)256 * K * 2);
    }
    _Float16* bufA = (_Float16*)alloc((size_t)N_NODES * F * 2);   // xw fp16
    float*    bufB = (float*)   alloc((size_t)N_NODES * F * 4);   // h fp32

    const int* src = ei;
    const int* dst = ei + N_EDGES;

    // ---- CSR build + dinv + weight prepack ----
    hipMemsetAsync(cnt, 0, N_NODES * 4, stream);
    hipMemsetAsync(out, 0, (size_t)N_GRAPHS * F * 4, stream);
    hipMemsetAsync(statsAll, 0, 5 * 2 * F * 4, stream);
    k_hist<<<(N_EDGES + 255) / 256, 256, 0, stream>>>(dst, cnt);
    k_dinv<<<(N_NODES + 255) / 256, 256, 0, stream>>>(cnt, dinv);
    k_scan1<<<SCAN_BLOCKS, 256, 0, stream>>>(cnt, rowptr, bsum);
    k_scan2<<<1, 256, 0, stream>>>(bsum);
    k_scan3<<<SCAN_BLOCKS, 256, 0, stream>>>(rowptr, bsum);
    hipMemsetAsync(cnt, 0, N_NODES * 4, stream);
    k_scatter<<<(N_EDGES + 255) / 256, 256, 0, stream>>>(src, dst, dinv, rowptr, cnt, esrc, enorm);
    for (int l = 0; l < 6; ++l) {
        int K = (l == 0) ? 128 : 256;
        k_pack<<<(256 * K + 255) / 256, 256, 0, stream>>>(W[l], Whi[l], Wlo[l], K);
    }

    const int aggGrid = (N_NODES + 15) / 16;   // 3125
    const float* hin = x;
    for (int l = 0; l < 6; ++l) {
        const int K = (l == 0) ? 128 : 256;
        const float* mk = (l == 0) ? nullptr : mulk;
        const float* ak = (l == 0) ? nullptr : addk;
        dim3 grid((N_NODES + 127) / 128, 2);
        k_gemm_mfma<<<grid, 256, 0, stream>>>(hin, Whi[l], Wlo[l], bufA, N_NODES, K, mk, ak);

        if (l < 5) {
            float* stats = statsAll + l * 2 * F;
            k_agg_fused<0><<<aggGrid, 256, 0, stream>>>(bufA, dinv, rowptr, esrc, enorm,
                                                        bias[l], bufB, stats, batch, out);
            k_bnfinalize<<<1, F, 0, stream>>>(stats, gamma[l], beta[l], mulk, addk);
            hin = bufB;
        } else {
            k_agg_fused<1><<<aggGrid, 256, 0, stream>>>(bufA, dinv, rowptr, esrc, enorm,
                                                        bias[l], nullptr, nullptr, batch, out);
        }
    }
}